// Round 8
// baseline (413.065 us; speedup 1.0000x reference)
//
#include <hip/hip_runtime.h>
#include <hip/hip_bf16.h>

#define D 128
#define CHUNK 4096          // edges per chunk in hist/binsort
#define BINSZ 128           // targets per bin

typedef __attribute__((ext_vector_type(8))) short bf16x8;  // 8 bf16 = 4 VGPRs
typedef __attribute__((ext_vector_type(4))) float f32x4;

__device__ __forceinline__ ushort f2bf(float f) {
    uint u = __float_as_uint(f);
    u += 0x7fffu + ((u >> 16) & 1u);   // RNE
    return (ushort)(u >> 16);
}

__device__ __forceinline__ int wave_incl_scan(int v) {
    int lane = threadIdx.x & 63;
#pragma unroll
    for (int off = 1; off < 64; off <<= 1) {
        int n = __shfl_up(v, off, 64);
        if (lane >= off) v += n;
    }
    return v;
}

// ---------------------------------------------------------------------------
// K1: pure streaming cast f32 -> bf16 for both node sets
// ---------------------------------------------------------------------------
__global__ __launch_bounds__(256) void cast_k(
        const float* __restrict__ xu, ushort* __restrict__ xbu, long long n4u,
        const float* __restrict__ xp, ushort* __restrict__ xbp, long long n4p) {
    long long g = (long long)blockIdx.x * 256 + threadIdx.x;
    long long gs = (long long)gridDim.x * 256;
    for (long long i = g; i < n4u; i += gs) {
        float4 v = ((const float4*)xu)[i];
        ushort4 o = {f2bf(v.x), f2bf(v.y), f2bf(v.z), f2bf(v.w)};
        ((ushort4*)xbu)[i] = o;
    }
    for (long long i = g; i < n4p; i += gs) {
        float4 v = ((const float4*)xp)[i];
        ushort4 o = {f2bf(v.x), f2bf(v.y), f2bf(v.z), f2bf(v.w)};
        ((ushort4*)xbp)[i] = o;
    }
}

// ---------------------------------------------------------------------------
// K2: per-chunk LDS histogram over bins -> cnt[bin][chunk]
// ---------------------------------------------------------------------------
__global__ __launch_bounds__(256) void hist_k(
        const int* __restrict__ etU, int EU, int* __restrict__ cntU, int NBu, int CBu,
        const int* __restrict__ etP, int EP, int* __restrict__ cntP, int NBp, int CBp) {
    __shared__ int h[800];
    const int* et; int E; int* cnt; int NB, CB, c;
    if (blockIdx.x < (unsigned)CBu) { et = etU; E = EU; cnt = cntU; NB = NBu; CB = CBu; c = blockIdx.x; }
    else { et = etP; E = EP; cnt = cntP; NB = NBp; CB = CBp; c = blockIdx.x - CBu; }
    for (int i = threadIdx.x; i < NB; i += 256) h[i] = 0;
    __syncthreads();
    int lo = c * CHUNK, hi = min(lo + CHUNK, E);
    for (int i = lo + threadIdx.x; i < hi; i += 256) atomicAdd(&h[et[i] >> 7], 1);
    __syncthreads();
    for (int i = threadIdx.x; i < NB; i += 256) cnt[(long long)i * CB + c] = h[i];
}

// ---------------------------------------------------------------------------
// K3: one wave per bin: exclusive-scan cnt[bin][*] in place; total -> tot[bin]
// ---------------------------------------------------------------------------
__global__ __launch_bounds__(256) void binscan_k(
        int* __restrict__ cntU, int* __restrict__ totU, int NBu, int CBu,
        int* __restrict__ cntP, int* __restrict__ totP, int NBp, int CBp) {
    int gw = (blockIdx.x * 256 + threadIdx.x) >> 6;
    int lane = threadIdx.x & 63;
    int* cnt; int* tot; int CB, bin;
    if (gw < NBu) { cnt = cntU; tot = totU; CB = CBu; bin = gw; }
    else {
        bin = gw - NBu;
        if (bin >= NBp) return;
        cnt = cntP; tot = totP; CB = CBp;
    }
    int* row = cnt + (long long)bin * CB;
    int carry = 0;
    for (int r = 0; r * 64 < CB; r++) {
        int i = r * 64 + lane;
        int v = (i < CB) ? row[i] : 0;
        int isc = wave_incl_scan(v);
        if (i < CB) row[i] = isc - v + carry;
        carry += __shfl(isc, 63, 64);
    }
    if (lane == 0) tot[bin] = carry;
}

// ---------------------------------------------------------------------------
// K4: block 0 = exclusive-scan bin totals -> binStart (wave0 user, wave1 poi);
//     blocks 1..32 = pack 4 weight matrices into MFMA B-fragment order.
// ---------------------------------------------------------------------------
__global__ __launch_bounds__(256) void mid_k(
        const int* __restrict__ totU, int* __restrict__ bstU, int NBu,
        const int* __restrict__ totP, int* __restrict__ bstP, int NBp,
        const float* __restrict__ W0, const float* __restrict__ W1,
        const float* __restrict__ W2, const float* __restrict__ W3,
        ushort* __restrict__ P) {
    if (blockIdx.x == 0) {
        if (threadIdx.x < 128) {
            int lane = threadIdx.x & 63;
            int w = threadIdx.x >> 6;
            const int* tot = w ? totP : totU;
            int* bst = w ? bstP : bstU;
            int nb = w ? NBp : NBu;
            int carry = 0;
            for (int r = 0; r * 64 < nb; r++) {
                int i = r * 64 + lane;
                int v = (i < nb) ? tot[i] : 0;
                int isc = wave_incl_scan(v);
                if (i < nb) bst[i] = isc - v + carry;
                carry += __shfl(isc, 63, 64);
            }
        }
        return;
    }
    int t = (blockIdx.x - 1) * 256 + threadIdx.x;
    if (t >= 4 * 2048) return;
    int w = t >> 11, r = t & 2047;
    int lane = r & 63, fi = r >> 6;
    int kk = fi >> 3, n0 = fi & 7;
    const float* W = (w == 0) ? W0 : (w == 1) ? W1 : (w == 2) ? W2 : W3;
    int col = n0 * 16 + (lane & 15);
    int kb = kk * 32 + (lane >> 4) * 8;
    bf16x8 v;
#pragma unroll
    for (int j = 0; j < 8; j++) v[j] = (short)f2bf(W[(kb + j) * D + col]);
    *(bf16x8*)&P[(long long)t * 8] = v;
}

// ---------------------------------------------------------------------------
// K5: bin-sort edges. LDS cursors = binStart[bin] + cnt[bin][chunk]; write
// packed (local_tgt<<17 | src) into the bin's contiguous region.
// ---------------------------------------------------------------------------
__global__ __launch_bounds__(256) void binsort_k(
        const int* __restrict__ esU, const int* __restrict__ etU, int EU,
        const int* __restrict__ cntU, const int* __restrict__ bstU,
        int* __restrict__ binU, int NBu, int CBu,
        const int* __restrict__ esP, const int* __restrict__ etP, int EP,
        const int* __restrict__ cntP, const int* __restrict__ bstP,
        int* __restrict__ binP, int NBp, int CBp) {
    __shared__ int cur[800];
    const int* es; const int* et; int E; const int* cnt; const int* bst;
    int* bnd; int NB, CB, c;
    if (blockIdx.x < (unsigned)CBu) {
        es = esU; et = etU; E = EU; cnt = cntU; bst = bstU; bnd = binU;
        NB = NBu; CB = CBu; c = blockIdx.x;
    } else {
        es = esP; et = etP; E = EP; cnt = cntP; bst = bstP; bnd = binP;
        NB = NBp; CB = CBp; c = blockIdx.x - CBu;
    }
    for (int i = threadIdx.x; i < NB; i += 256)
        cur[i] = bst[i] + cnt[(long long)i * CB + c];
    __syncthreads();
    int lo = c * CHUNK, hi = min(lo + CHUNK, E);
    for (int i = lo + threadIdx.x; i < hi; i += 256) {
        int t = et[i];
        int s = es[i];
        int pos = atomicAdd(&cur[t >> 7], 1);
        bnd[pos] = ((t & 127) << 17) | s;
    }
}

// ---------------------------------------------------------------------------
// K6: FUSED per-bin kernel: CSR-in-block (perm to global, ~36 KB LDS only) +
// gather-mean + dual MFMA GEMM + relu.  512 threads = 8 waves; bin = 128 rows.
//   OUT[r] = relu( Xb[r]@Wt + mean_r@Ws )
// LDS kept under 40 KB -> 4 blocks/CU (2048 thr = CU max) for the
// latency-bound gather phase.
// ---------------------------------------------------------------------------
__global__ __launch_bounds__(512) void fused_k(
        const int* __restrict__ bndU, const int* __restrict__ bstU,
        const int* __restrict__ totU, int NBu, int* __restrict__ permU,
        const ushort* __restrict__ gsrcU, const ushort* __restrict__ XbU,
        const ushort* __restrict__ WtPU, const ushort* __restrict__ WsPU,
        float* __restrict__ OUTU, int n_u,
        const int* __restrict__ bndP, const int* __restrict__ bstP,
        const int* __restrict__ totP, int* __restrict__ permP,
        const ushort* __restrict__ gsrcP, const ushort* __restrict__ XbP,
        const ushort* __restrict__ WtPP, const ushort* __restrict__ WsPP,
        float* __restrict__ OUTP, int n_p) {
    __shared__ ushort agg[128][136];      // ~34.8 KB bf16 means (pad vs conflicts)
    __shared__ int h[128], sbase[128], scur[128];

    const int* bnd; const int* bst; const int* tot; int* perm;
    const ushort* gsrc; const ushort* Xb; const ushort* WtP; const ushort* WsP;
    float* OUT; int n, bb;
    if (blockIdx.x < (unsigned)NBu) {
        bnd = bndU; bst = bstU; tot = totU; perm = permU; gsrc = gsrcU; Xb = XbU;
        WtP = WtPU; WsP = WsPU; OUT = OUTU; n = n_u; bb = blockIdx.x;
    } else {
        bb = blockIdx.x - NBu;
        bnd = bndP; bst = bstP; tot = totP; perm = permP; gsrc = gsrcP; Xb = XbP;
        WtP = WtPP; WsP = WsPP; OUT = OUTP; n = n_p;
    }
    const int tid = threadIdx.x;
    const int lane = tid & 63;
    const int wv = tid >> 6;              // 0..7
    const int t0 = bb << 7;               // global target base of this bin
    const int s0 = bst[bb];
    const int cnt = tot[bb];

    // --- per-target histogram ---
    if (tid < 128) h[tid] = 0;
    __syncthreads();
    for (int i = s0 + tid; i < s0 + cnt; i += 512)
        atomicAdd(&h[bnd[i] >> 17], 1);
    __syncthreads();
    // --- exact 128-entry exclusive scan (wave 0) ---
    if (tid < 64) {
        int carry = 0;
#pragma unroll
        for (int r = 0; r < 2; r++) {
            int i = r * 64 + tid;
            int v = h[i];
            int isc = wave_incl_scan(v);
            sbase[i] = isc - v + carry;
            carry += __shfl(isc, 63, 64);
        }
    }
    __syncthreads();
    if (tid < 128) scur[tid] = sbase[tid];
    __syncthreads();
    // --- scatter src ids, target-sorted, into the bin's global perm region ---
    for (int i = s0 + tid; i < s0 + cnt; i += 512) {
        int v = bnd[i];
        int pos = atomicAdd(&scur[v >> 17], 1);
        perm[s0 + pos] = v & 0x1FFFF;
    }
    __syncthreads();   // drains vmcnt: perm writes visible to this block

    // --- gather-mean: wave wv owns local rows [wv*16, wv*16+16) ---
    const uint* x2 = (const uint*)gsrc;
#pragma unroll 1
    for (int q = 0; q < 16; q++) {
        int lt = wv * 16 + q;
        int b0 = s0 + sbase[lt], dg = h[lt];
        float ax = 0.f, ay = 0.f;
        int j = 0;
        for (; j + 4 <= dg; j += 4) {
            int sa = perm[b0 + j],     sb = perm[b0 + j + 1];
            int sc = perm[b0 + j + 2], sd = perm[b0 + j + 3];
            uint va = x2[sa * 64 + lane], vb = x2[sb * 64 + lane];
            uint vc = x2[sc * 64 + lane], vd = x2[sd * 64 + lane];
            ax += (__uint_as_float(va << 16) + __uint_as_float(vb << 16)) +
                  (__uint_as_float(vc << 16) + __uint_as_float(vd << 16));
            ay += (__uint_as_float(va & 0xffff0000u) + __uint_as_float(vb & 0xffff0000u)) +
                  (__uint_as_float(vc & 0xffff0000u) + __uint_as_float(vd & 0xffff0000u));
        }
        for (; j < dg; j++) {
            int s = perm[b0 + j];
            uint v = x2[s * 64 + lane];
            ax += __uint_as_float(v << 16);
            ay += __uint_as_float(v & 0xffff0000u);
        }
        float scl = 1.0f / fmaxf((float)dg, 1.0f);
        uint o = ((uint)f2bf(ay * scl) << 16) | (uint)f2bf(ax * scl);
        *(uint*)&agg[lt][2 * lane] = o;
    }
    __syncthreads();

    // --- dual GEMM: acc = Xb_rows @ Wt + agg @ Ws ; relu; store ---
    const int l15 = lane & 15, lhi = lane >> 4;
    f32x4 acc[8];
#pragma unroll
    for (int nn = 0; nn < 8; nn++) acc[nn] = (f32x4){0.f, 0.f, 0.f, 0.f};

    int rA = t0 + wv * 16 + l15;
    if (rA > n - 1) rA = n - 1;
#pragma unroll
    for (int kk = 0; kk < 4; kk++) {
        bf16x8 a0 = *(const bf16x8*)&Xb[(long long)rA * D + kk * 32 + lhi * 8];
#pragma unroll
        for (int nn = 0; nn < 8; nn++) {
            bf16x8 b = *(const bf16x8*)&WtP[(long long)((kk * 8 + nn) * 64 + lane) * 8];
            acc[nn] = __builtin_amdgcn_mfma_f32_16x16x32_bf16(a0, b, acc[nn], 0, 0, 0);
        }
    }
    const int rl = wv * 16 + l15;
#pragma unroll
    for (int kk = 0; kk < 4; kk++) {
        bf16x8 a1 = *(const bf16x8*)&agg[rl][kk * 32 + lhi * 8];
#pragma unroll
        for (int nn = 0; nn < 8; nn++) {
            bf16x8 b = *(const bf16x8*)&WsP[(long long)((kk * 8 + nn) * 64 + lane) * 8];
            acc[nn] = __builtin_amdgcn_mfma_f32_16x16x32_bf16(a1, b, acc[nn], 0, 0, 0);
        }
    }

#pragma unroll
    for (int nn = 0; nn < 8; nn++)
#pragma unroll
        for (int ri = 0; ri < 4; ri++) {
            int r = t0 + wv * 16 + lhi * 4 + ri;
            if (r < n)
                OUT[(long long)r * D + nn * 16 + l15] = fmaxf(acc[nn][ri], 0.f);
        }
}

extern "C" void kernel_launch(void* const* d_in, const int* in_sizes, int n_in,
                              void* d_out, int out_size, void* d_ws, size_t ws_size,
                              hipStream_t stream) {
    const float* x_user    = (const float*)d_in[0];
    const float* x_poi     = (const float*)d_in[1];
    const float* W_u2p_src = (const float*)d_in[2];
    const float* W_u2p_tgt = (const float*)d_in[3];
    const float* W_p2u_src = (const float*)d_in[4];
    const float* W_p2u_tgt = (const float*)d_in[5];
    const int* e_u2p_src   = (const int*)d_in[6];
    const int* e_u2p_tgt   = (const int*)d_in[7];
    const int* e_p2u_src   = (const int*)d_in[8];
    const int* e_p2u_tgt   = (const int*)d_in[9];

    const int n_user = in_sizes[0] / D;   // 100000
    const int n_poi  = in_sizes[1] / D;   // 50000
    const int E1 = in_sizes[6];           // u2p (targets = poi, srcs = user)
    const int E2 = in_sizes[8];           // p2u (targets = user, srcs = poi)

    float* out = (float*)d_out;
    float* out_user = out;
    float* out_poi  = out + (long long)n_user * D;

    const int NBu = (n_user + BINSZ - 1) / BINSZ;   // 782
    const int NBp = (n_poi + BINSZ - 1) / BINSZ;    // 391
    const int CBu = (E2 + CHUNK - 1) / CHUNK;
    const int CBp = (E1 + CHUNK - 1) / CHUNK;

    // ---- workspace layout (~56 MB) ----
    char* w = (char*)d_ws;
    ushort* xb_user = (ushort*)w;  w += (size_t)n_user * D * 2;
    ushort* xb_poi  = (ushort*)w;  w += (size_t)n_poi  * D * 2;
    ushort* Wpack   = (ushort*)w;  w += (size_t)4 * 2048 * 8 * 2;
    int* binU       = (int*)w;     w += (size_t)E2 * 4;
    int* binP       = (int*)w;     w += (size_t)E1 * 4;
    int* permU      = (int*)w;     w += (size_t)E2 * 4;
    int* permP      = (int*)w;     w += (size_t)E1 * 4;
    int* cntU       = (int*)w;     w += (size_t)NBu * CBu * 4;
    int* cntP       = (int*)w;     w += (size_t)NBp * CBp * 4;
    int* totU       = (int*)w;     w += (size_t)NBu * 4;
    int* totP       = (int*)w;     w += (size_t)NBp * 4;
    int* bstU       = (int*)w;     w += (size_t)NBu * 4;
    int* bstP       = (int*)w;     w += (size_t)NBp * 4;

    ushort* WtP_user = Wpack + 0 * 2048 * 8;   // W_p2u_tgt
    ushort* WsP_user = Wpack + 1 * 2048 * 8;   // W_p2u_src
    ushort* WtP_poi  = Wpack + 2 * 2048 * 8;   // W_u2p_tgt
    ushort* WsP_poi  = Wpack + 3 * 2048 * 8;   // W_u2p_src

    // 1) streaming cast
    cast_k<<<2048, 256, 0, stream>>>(x_user, xb_user, (long long)n_user * D / 4,
                                     x_poi, xb_poi, (long long)n_poi * D / 4);

    // 2) per-chunk bin histograms (both edge types)
    hist_k<<<CBu + CBp, 256, 0, stream>>>(e_p2u_tgt, E2, cntU, NBu, CBu,
                                          e_u2p_tgt, E1, cntP, NBp, CBp);

    // 3) per-bin chunk scans
    binscan_k<<<(NBu + NBp + 3) / 4, 256, 0, stream>>>(cntU, totU, NBu, CBu,
                                                       cntP, totP, NBp, CBp);

    // 4) bin-start scan + weight pack
    mid_k<<<33, 256, 0, stream>>>(totU, bstU, NBu, totP, bstP, NBp,
                                  W_p2u_tgt, W_p2u_src, W_u2p_tgt, W_u2p_src, Wpack);

    // 5) bin-sort edges (packed local_tgt|src)
    binsort_k<<<CBu + CBp, 256, 0, stream>>>(
        e_p2u_src, e_p2u_tgt, E2, cntU, bstU, binU, NBu, CBu,
        e_u2p_src, e_u2p_tgt, E1, cntP, bstP, binP, NBp, CBp);

    // 6) fused per-bin CSR + gather-mean + dual MFMA GEMM + relu
    fused_k<<<NBu + NBp, 512, 0, stream>>>(
        binU, bstU, totU, NBu, permU, xb_poi, xb_user,
        WtP_user, WsP_user, out_user, n_user,
        binP, bstP, totP, permP, xb_user, xb_poi,
        WtP_poi, WsP_poi, out_poi, n_poi);
}